// Round 6
// baseline (6825.013 us; speedup 1.0000x reference)
//
#include <hip/hip_runtime.h>
#include <cstdint>

typedef short bf16x8 __attribute__((ext_vector_type(8)));
typedef float f32x4 __attribute__((ext_vector_type(4)));

#define MFMA(a,b,c) __builtin_amdgcn_mfma_f32_16x16x32_bf16((a),(b),(c),0,0,0)

// ---------------- ws layout (bytes) ----------------
constexpr int FR = 512;                          // bf16 elems per fragment (64 lanes x 8)
constexpr size_t OP2   = 0;                                  // P2 f32 row-major [8192][672]
constexpr size_t SZP2  = (size_t)8192*672*4;                 // 22,020,096
constexpr size_t OWSUM = OP2 + SZP2;                         // [25ks][42nt][512] bf16
constexpr size_t SZWSUM= (size_t)25*42*FR*2;
constexpr size_t OWEAM = OWSUM + SZWSUM;                     // enc A-side weights mu [28][21][512]
constexpr size_t SZWEA = (size_t)28*21*FR*2;
constexpr size_t OWEAL = OWEAM + SZWEA;
constexpr size_t OWEBM = OWEAL + SZWEA;                      // enc h-side [4][21][512]
constexpr size_t SZWEB = (size_t)4*21*FR*2;
constexpr size_t OWEBL = OWEBM + SZWEB;
constexpr size_t OWH   = OWEBL + SZWEB;                      // heads [8][14][512]
constexpr size_t SZWH  = (size_t)8*14*FR*2;
constexpr size_t OWD   = OWH + SZWH;                         // dec [8][21][512]
constexpr size_t SZWD  = (size_t)8*21*FR*2;
constexpr size_t OWW   = OWD + SZWD;                         // write [4][49][512]
constexpr size_t SZWW  = (size_t)4*49*FR*2;
constexpr size_t OBP2  = OWW + SZWW;                         // f32 bias frags
constexpr size_t OBGHN = OBP2 + (size_t)42*256*4;
constexpr size_t OBDI  = OBGHN + (size_t)2*7*256*4;
constexpr size_t OBDHN = OBDI + (size_t)21*256*4;
constexpr size_t OBWR  = OBDHN + (size_t)7*256*4;
constexpr size_t OBH   = OBWR + (size_t)49*256*4;            // end ~25.1 MB

__device__ __forceinline__ float sigf(float x){ return 1.0f/(1.0f+__expf(-x)); }
__device__ __forceinline__ float tanhfast(float x){ return 1.0f - 2.0f/(__expf(2.0f*x)+1.0f); }
__device__ __forceinline__ float bf2f(unsigned short u){ return __uint_as_float(((unsigned int)u)<<16); }
__device__ __forceinline__ unsigned short f2bf(float f){ unsigned int x = __float_as_uint(f); return (unsigned short)((x + 0x8000u) >> 16); }

// ---------------- weight / bias fragment packing ----------------
__global__ void init_pack(
    const float* __restrict__ ihmu, const float* __restrict__ whhmu,
    const float* __restrict__ bihmu, const float* __restrict__ bhhmu,
    const float* __restrict__ ihlv, const float* __restrict__ whhlv,
    const float* __restrict__ bihlv, const float* __restrict__ bhhlv,
    const float* __restrict__ wmu, const float* __restrict__ bmu,
    const float* __restrict__ wlv, const float* __restrict__ blv,
    const float* __restrict__ ihd, const float* __restrict__ whhd,
    const float* __restrict__ bihd, const float* __restrict__ bhhd,
    const float* __restrict__ wwr, const float* __restrict__ bwr,
    char* __restrict__ wsb)
{
  int u = blockIdx.x*256 + threadIdx.x;
  if (u < 1469440) {
    int v = u; size_t off; int NT; int region;
    if      (v < 537600)            { region=0; off=OWSUM; NT=42; }
    else if ((v-=537600) < 301056)  { region=1; off=OWEAM; NT=21; }
    else if ((v-=301056) < 301056)  { region=2; off=OWEAL; NT=21; }
    else if ((v-=301056) < 43008)   { region=3; off=OWEBM; NT=21; }
    else if ((v-=43008)  < 43008)   { region=4; off=OWEBL; NT=21; }
    else if ((v-=43008)  < 57344)   { region=5; off=OWH;   NT=14; }
    else if ((v-=57344)  < 86016)   { region=6; off=OWD;   NT=21; }
    else    { v-=86016;   region=7; off=OWW;   NT=49; }
    int ks = v / (NT*512); int rem = v - ks*(NT*512);
    int nt = rem >> 9; int li = rem & 511;
    int l = li >> 3, e = li & 7;
    int k = ks*32 + ((l>>4)<<3) + e;
    int c = l & 15;
    float val = 0.f;
    if (region==0) {
      int gru = nt/21, ntg = nt%21, gate = ntg/7, j = (ntg%7)*16 + c;
      if (j<100 && k<784) { const float* IH = gru? ihlv : ihmu; int jj = gate*100+j;
        val = IH[(size_t)jj*1668 + k] + IH[(size_t)jj*1668 + 784 + k]; }
    } else if (region==1 || region==2) {
      const float* IH = (region==2)? ihlv : ihmu;
      int gate = nt/7, j = (nt%7)*16 + c;
      if (j<100) { int jj = gate*100+j;
        if (k<784)      val = -IH[(size_t)jj*1668 + 784 + k];
        else if (k<884) val =  IH[(size_t)jj*1668 + 1568 + (k-784)]; }
    } else if (region==3 || region==4) {
      const float* WHH = (region==4)? whhlv : whhmu;
      int gate = nt/7, j = (nt%7)*16 + c;
      if (j<100 && k<100) val = WHH[(gate*100+j)*100 + k];
    } else if (region==5) {
      int grp = nt/7, j = (nt%7)*16 + c;
      if (j<100) {
        if (grp==0) { if (k<100) val = wmu[j*100+k]; }
        else        { if (k>=128 && k<228) val = wlv[j*100 + (k-128)]; }
      }
    } else if (region==6) {
      int gate = nt/7, j = (nt%7)*16 + c;
      if (j<100) { int jj = gate*100+j;
        if (k<100)               val = ihd[jj*100+k];
        else if (k>=128 && k<228) val = whhd[jj*100 + (k-128)]; }
    } else {
      int n = nt*16 + c;
      if (k<100) val = wwr[n*100+k];
    }
    *(unsigned short*)(wsb + off + (size_t)v*2) = f2bf(val);
    return;
  }
  u -= 1469440;
  if (u >= 37632) return;
  float val = 0.f; size_t off; int v = u;
  if (v < 10752) { off = OBP2;
    int nt = v>>8, li = v&255, l = li>>2, c = l&15;
    int gru = nt/21, ntg = nt%21, gate = ntg/7, j = (ntg%7)*16 + c;
    if (j<100) {
      const float* BI = gru? bihlv : bihmu; const float* BH = gru? bhhlv : bhhmu;
      val = BI[gate*100+j] + ((gate<2)? BH[gate*100+j] : 0.f);
    }
  } else if ((v-=10752) < 3584) { off = OBGHN;
    int g = v/1792, r2 = v - g*1792, p = r2>>8, li = r2&255, l = li>>2, c = l&15;
    int j = p*16+c;
    if (j<100) val = (g? bhhlv : bhhmu)[200+j];
  } else if ((v-=3584) < 5376) { off = OBDI;
    int nt = v>>8, li = v&255, l = li>>2, c = l&15;
    int gate = nt/7, j = (nt%7)*16+c;
    if (j<100) val = (gate<2)? (bihd[gate*100+j]+bhhd[gate*100+j]) : bihd[200+j];
  } else if ((v-=5376) < 1792) { off = OBDHN;
    int p = v>>8, li = v&255, l = li>>2, c = l&15; int j = p*16+c;
    if (j<100) val = bhhd[200+j];
  } else if ((v-=1792) < 12544) { off = OBWR;
    int nt = v>>8, li = v&255, l = li>>2, c = l&15;
    val = bwr[nt*16+c];
  } else { v -= 12544; off = OBH;
    int nt = v>>8, li = v&255, l = li>>2, c = l&15;
    int grp = nt/7, j = (nt%7)*16+c;
    if (j<100) val = grp? blv[j] : bmu[j];
  }
  *(float*)(wsb + off + (size_t)v*4) = val;
}

// ---------------- P2 = x@(W1+W2)^T + bias -> row-major f32 [8192][672] ----------------
__global__ __launch_bounds__(512) void init_p2(const float* __restrict__ x, char* __restrict__ wsb)
{
  __shared__ char xt[16*1600];
  const int tid = threadIdx.x, l = tid&63, w = tid>>6;
  const int lr = l&15, lg = l>>4;
  const int rt = blockIdx.x;
  for (int i = tid; i < 16*800; i += 512) {
    int row = i/800, col = i - row*800;
    unsigned short hv = 0;
    if (col < 784) hv = f2bf(x[(size_t)(rt*16+row)*784 + col]);
    *(unsigned short*)(xt + ((row*1600 + col*2) ^ ((row&7)<<4))) = hv;
  }
  __syncthreads();
  const char* WS = wsb + OWSUM;
  float* P2f = (float*)(wsb + OP2);
  for (int nt = w; nt < 42; nt += 8) {
    f32x4 acc = *(const f32x4*)(wsb + OBP2 + (size_t)(nt*256 + l*4)*4);
    const char* wp = WS + (size_t)(nt*512 + l*8)*2;
    #pragma unroll 5
    for (int ks = 0; ks < 25; ++ks) {
      bf16x8 a = *(const bf16x8*)(xt + ((lr*1600 + ks*64 + lg*16) ^ ((lr&7)<<4)));
      bf16x8 b = *(const bf16x8*)(wp + (size_t)ks*42*512*2);
      acc = MFMA(a,b,acc);
    }
    int gru = nt/21, ntg = nt%21, gate = ntg/7, p = ntg%7;
    int j = p*16 + lr;
    int cbase = (gru*3 + gate)*112 + j;
    #pragma unroll
    for (int e=0;e<4;++e) {
      int row = rt*16 + lg*4 + e;
      P2f[(size_t)row*672 + cbase] = acc[e];
    }
  }
}

// ---------------- main persistent kernel: 768 blocks x {11,10} rows ----------------
__global__ __launch_bounds__(512,6) void draw_main(
    const float* __restrict__ noise, const char* __restrict__ wsb, float* __restrict__ out)
{
  extern __shared__ char sm[];
  char* Aenc = sm;               // [16][1792 B] bf16: sigc(784) | hdec(100) | pad
  char* Ahml = sm + 28672;       // [16][512 B]  bf16: hmu(100) pad | hlv(100) pad
  char* Adec = sm + 36864;       // [16][512 B]  bf16: z(100) pad | hdec(100) pad
  unsigned short* muv16 = (unsigned short*)(sm + 45056);  // [11][100] mu | [11][100] lv bf16

  const int tid = threadIdx.x, l = tid&63, w = tid>>6;
  const int lr = l&15, lg = l>>4;
  const int blk = blockIdx.x;
  const int r0 = (blk < 512) ? blk*11 : 5632 + (blk-512)*10;
  const int nr = (blk < 512) ? 11 : 10;

  float* out_c  = out;
  float* out_mu = out + (size_t)8192*784;
  float* out_lv = out_mu + (size_t)32*8192*100;
  const float* P2f = (const float*)(wsb + OP2);

  for (int i = tid; i < 16*896; i += 512) {
    int row = i/896, col = i - row*896;
    unsigned short v = (col<784)? (unsigned short)0x3F00 : (unsigned short)0;
    *(unsigned short*)(Aenc + ((row*1792 + col*2) ^ ((row&7)<<4))) = v;
  }
  for (int i = tid; i < 16*256; i += 512) {
    int row = i>>8, col = i&255;
    int a = (row*512 + col*2) ^ ((row&7)<<4);
    *(unsigned short*)(Ahml + a) = 0;
    *(unsigned short*)(Adec + a) = 0;
  }

  // per-wave job constants
  const int pm = w;            const bool actm = pm < 7;
  const int plv = (w+2)&7;     const bool actl = plv < 7;
  const int pd  = (w+4)&7;     const bool actd = pd < 7;
  const int axor = (lr&7)<<4;

  const f32x4 z4 = {0.f,0.f,0.f,0.f};
  f32x4 creg[7];
  #pragma unroll
  for (int q=0;q<7;++q) creg[q] = z4;
  f32x4 hm = z4, hl = z4, hd = z4;
  __syncthreads();

  for (int t = 0; t < 32; ++t) {
    // ===== merged encoder GEMMs (mu + lv in one phase) =====
    f32x4 ar0=z4, az0=z4, an0=z4, ahn0=z4, ar1=z4, az1=z4, an1=z4, ahn1=z4;
    if (actm) {
      int j = pm*16 + lr;
      #pragma unroll
      for (int e=0;e<4;++e) {
        int rw = lg*4 + e;
        const float* pr = P2f + (size_t)(r0 + ((rw<nr)? rw : 0))*672 + j;
        ar0[e] = pr[0]; az0[e] = pr[112]; an0[e] = pr[224];
      }
      ahn0 = *(const f32x4*)(wsb + OBGHN + (size_t)(pm*256 + l*4)*4);
    }
    if (actl) {
      int j = plv*16 + lr;
      #pragma unroll
      for (int e=0;e<4;++e) {
        int rw = lg*4 + e;
        const float* pr = P2f + (size_t)(r0 + ((rw<nr)? rw : 0))*672 + 336 + j;
        ar1[e] = pr[0]; az1[e] = pr[112]; an1[e] = pr[224];
      }
      ahn1 = *(const f32x4*)(wsb + OBGHN + (size_t)((7+plv)*256 + l*4)*4);
    }
    {
      const char* wr0 = wsb + OWEAM + (size_t)(pm*512 + l*8)*2;
      const char* wz0 = wr0 + (size_t)7*512*2;
      const char* wn0 = wr0 + (size_t)14*512*2;
      const char* wr1 = wsb + OWEAL + (size_t)(plv*512 + l*8)*2;
      const char* wz1 = wr1 + (size_t)7*512*2;
      const char* wn1 = wr1 + (size_t)14*512*2;
      int abase = lr*1792 + lg*16;
      #pragma unroll 4
      for (int ks=0; ks<28; ++ks) {
        bf16x8 a = *(const bf16x8*)(Aenc + ((abase + ks*64) ^ axor));
        size_t so = (size_t)ks*21*512*2;
        if (actm) {
          ar0 = MFMA(a, *(const bf16x8*)(wr0+so), ar0);
          az0 = MFMA(a, *(const bf16x8*)(wz0+so), az0);
          an0 = MFMA(a, *(const bf16x8*)(wn0+so), an0);
        }
        if (actl) {
          ar1 = MFMA(a, *(const bf16x8*)(wr1+so), ar1);
          az1 = MFMA(a, *(const bf16x8*)(wz1+so), az1);
          an1 = MFMA(a, *(const bf16x8*)(wn1+so), an1);
        }
      }
      const char* vr0 = wsb + OWEBM + (size_t)(pm*512 + l*8)*2;
      const char* vz0 = vr0 + (size_t)7*512*2;
      const char* vn0 = vr0 + (size_t)14*512*2;
      const char* vr1 = wsb + OWEBL + (size_t)(plv*512 + l*8)*2;
      const char* vz1 = vr1 + (size_t)7*512*2;
      const char* vn1 = vr1 + (size_t)14*512*2;
      int hb = lr*512 + lg*16;
      #pragma unroll
      for (int ks=0; ks<4; ++ks) {
        size_t so = (size_t)ks*21*512*2;
        if (actm) {
          bf16x8 a = *(const bf16x8*)(Ahml + ((hb + ks*64) ^ axor));
          ar0  = MFMA(a, *(const bf16x8*)(vr0+so), ar0);
          az0  = MFMA(a, *(const bf16x8*)(vz0+so), az0);
          ahn0 = MFMA(a, *(const bf16x8*)(vn0+so), ahn0);
        }
        if (actl) {
          bf16x8 a = *(const bf16x8*)(Ahml + ((hb + 256 + ks*64) ^ axor));
          ar1  = MFMA(a, *(const bf16x8*)(vr1+so), ar1);
          az1  = MFMA(a, *(const bf16x8*)(vz1+so), az1);
          ahn1 = MFMA(a, *(const bf16x8*)(vn1+so), ahn1);
        }
      }
    }
    __syncthreads();                       // B1: all Ahml reads done
    if (actm) {
      int col = pm*16 + lr;
      #pragma unroll
      for (int e=0;e<4;++e) {
        float rg = sigf(ar0[e]);
        float zg = sigf(az0[e]);
        float nn = tanhfast(fmaf(rg, ahn0[e], an0[e]));
        float hnew = nn + zg*(hm[e] - nn);
        hm[e] = hnew;
        if (col < 100) {
          int row = lg*4 + e;
          *(unsigned short*)(Ahml + ((row*512 + col*2) ^ ((row&7)<<4))) = f2bf(hnew);
        }
      }
    }
    if (actl) {
      int col = plv*16 + lr;
      #pragma unroll
      for (int e=0;e<4;++e) {
        float rg = sigf(ar1[e]);
        float zg = sigf(az1[e]);
        float nn = tanhfast(fmaf(rg, ahn1[e], an1[e]));
        float hnew = nn + zg*(hl[e] - nn);
        hl[e] = hnew;
        if (col < 100) {
          int row = lg*4 + e;
          *(unsigned short*)(Ahml + ((row*512 + (128+col)*2) ^ ((row&7)<<4))) = f2bf(hnew);
        }
      }
    }
    __syncthreads();                       // B2: hmu/hlv ready

    // ===== heads + reparameterize =====
    if (w < 7) {
      int p = w;
      int col = p*16 + lr;
      float noz[4] = {0.f,0.f,0.f,0.f};
      if (col < 100) {
        #pragma unroll
        for (int e=0;e<4;++e) {
          int row = lg*4 + e;
          if (row < nr)
            noz[e] = __builtin_nontemporal_load(noise + (size_t)t*819200 + (size_t)(r0+row)*100 + col);
        }
      }
      f32x4 am = *(const f32x4*)(wsb + OBH + (size_t)(p*256 + l*4)*4);
      f32x4 al = *(const f32x4*)(wsb + OBH + (size_t)((7+p)*256 + l*4)*4);
      const char* WH = wsb + OWH;
      int hb = lr*512 + lg*16;
      #pragma unroll
      for (int ks=0; ks<4; ++ks) {
        bf16x8 a0 = *(const bf16x8*)(Ahml + ((hb + ks*64) ^ axor));
        bf16x8 a1 = *(const bf16x8*)(Ahml + ((hb + 256 + ks*64) ^ axor));
        am = MFMA(a0, *(const bf16x8*)(WH + ((size_t)(ks*14+p)*512 + l*8)*2), am);
        al = MFMA(a1, *(const bf16x8*)(WH + ((size_t)((ks+4)*14+7+p)*512 + l*8)*2), al);
      }
      if (col < 100) {
        #pragma unroll
        for (int e=0;e<4;++e) {
          int row = lg*4 + e;
          float m  = fmaxf(am[e], 0.f);
          float lv = fmaxf(al[e], 0.f);
          if (row < nr) {
            muv16[row*100 + col]        = f2bf(m);
            muv16[1100 + row*100 + col] = f2bf(lv);
          }
          float zz = fmaf(noz[e], __expf(0.5f*lv), m);
          *(unsigned short*)(Adec + ((row*512 + col*2) ^ ((row&7)<<4))) = f2bf(zz);
        }
      }
    }
    __syncthreads();                       // B3: muv + z ready

    // ===== dense NT store of mu/lv + decoder GRU gates =====
    {
      int nq = nr*25;
      size_t mb = (size_t)t*819200 + (size_t)r0*100;
      for (int i = tid; i < 2*nq; i += 512) {
        bool isMu = (i < nq);
        int k = isMu ? i : i - nq;
        int off = (isMu ? 0 : 1100) + k*4;
        f32x4 v;
        #pragma unroll
        for (int j2=0;j2<4;++j2) v[j2] = bf2f(muv16[off + j2]);
        __builtin_nontemporal_store(v, (f32x4*)((isMu ? out_mu : out_lv) + mb) + k);
      }
      f32x4 dr=z4, dz=z4, dn=z4, dhn=z4;
      if (actd) {
        dr  = *(const f32x4*)(wsb + OBDI  + (size_t)(pd*256 + l*4)*4);
        dz  = *(const f32x4*)(wsb + OBDI  + (size_t)((pd+7)*256 + l*4)*4);
        dn  = *(const f32x4*)(wsb + OBDI  + (size_t)((pd+14)*256 + l*4)*4);
        dhn = *(const f32x4*)(wsb + OBDHN + (size_t)(pd*256 + l*4)*4);
        const char* br = wsb + OWD + (size_t)(pd*512 + l*8)*2;
        const char* bz = br + (size_t)7*512*2;
        const char* bn = br + (size_t)14*512*2;
        int abase = lr*512 + lg*16;
        #pragma unroll
        for (int ks=0; ks<8; ++ks) {
          bf16x8 a = *(const bf16x8*)(Adec + ((abase + ks*64) ^ axor));
          size_t so = (size_t)ks*21*512*2;
          dr = MFMA(a, *(const bf16x8*)(br+so), dr);
          dz = MFMA(a, *(const bf16x8*)(bz+so), dz);
          if (ks<4) dn  = MFMA(a, *(const bf16x8*)(bn+so), dn);
          else      dhn = MFMA(a, *(const bf16x8*)(bn+so), dhn);
        }
      }
      __syncthreads();                     // B4: all Adec reads done
      if (actd) {
        int col = pd*16 + lr;
        #pragma unroll
        for (int e=0;e<4;++e) {
          float rg = sigf(dr[e]);
          float zg = sigf(dz[e]);
          float nn = tanhfast(fmaf(rg, dhn[e], dn[e]));
          float hnew = nn + zg*(hd[e] - nn);
          hd[e] = hnew;
          if (col < 100) {
            int row = lg*4 + e;
            unsigned short hb2 = f2bf(hnew);
            *(unsigned short*)(Adec + ((row*512 + (128+col)*2) ^ ((row&7)<<4))) = hb2;
            *(unsigned short*)(Aenc + ((row*1792 + (784+col)*2) ^ ((row&7)<<4))) = hb2;
          }
        }
      }
    }
    __syncthreads();                       // B5: new hdec visible

    // ===== canvas write GEMM: c += hdec @ Wwrite^T + bwrite =====
    {
      const char* WW = wsb + OWW;
      #pragma unroll
      for (int rep=0; rep<7; ++rep) {
        int nt = w + rep*8;
        if (nt < 49) {
          f32x4 c = creg[rep];
          int abase = lr*512 + 256 + lg*16;
          #pragma unroll
          for (int ks=0; ks<4; ++ks) {
            bf16x8 a = *(const bf16x8*)(Adec + ((abase + ks*64) ^ axor));
            c = MFMA(a, *(const bf16x8*)(WW + ((size_t)(ks*49+nt)*512 + l*8)*2), c);
          }
          f32x4 bw = *(const f32x4*)(wsb + OBWR + (size_t)(nt*256 + l*4)*4);
          c = c + bw;
          creg[rep] = c;
          #pragma unroll
          for (int e=0;e<4;++e) {
            float s = sigf(c[e]);
            int orow = lg*4 + e;
            int col = nt*16 + lr;
            if (t < 31) {
              *(unsigned short*)(Aenc + ((orow*1792 + col*2) ^ ((orow&7)<<4))) = f2bf(s);
            } else if (orow < nr) {
              __builtin_nontemporal_store(s, out_c + (size_t)(r0+orow)*784 + col);
            }
          }
        }
      }
    }
    __syncthreads();                       // B6: sigc ready for next step
  }
}

extern "C" void kernel_launch(void* const* d_in, const int* in_sizes, int n_in,
                              void* d_out, int out_size, void* d_ws, size_t ws_size,
                              hipStream_t stream) {
  (void)in_sizes; (void)n_in; (void)out_size; (void)ws_size;
  const float* x      = (const float*)d_in[0];
  const float* noise  = (const float*)d_in[1];
  const float* ih_mu  = (const float*)d_in[2];
  const float* whh_mu = (const float*)d_in[3];
  const float* bih_mu = (const float*)d_in[4];
  const float* bhh_mu = (const float*)d_in[5];
  const float* ih_lv  = (const float*)d_in[6];
  const float* whh_lv = (const float*)d_in[7];
  const float* bih_lv = (const float*)d_in[8];
  const float* bhh_lv = (const float*)d_in[9];
  const float* wmu    = (const float*)d_in[10];
  const float* bmu    = (const float*)d_in[11];
  const float* wlv    = (const float*)d_in[12];
  const float* blv    = (const float*)d_in[13];
  const float* wih_dec= (const float*)d_in[14];
  const float* whh_dec= (const float*)d_in[15];
  const float* bih_dec= (const float*)d_in[16];
  const float* bhh_dec= (const float*)d_in[17];
  const float* wwrite = (const float*)d_in[18];
  const float* bwrite = (const float*)d_in[19];
  char* wsb = (char*)d_ws;
  float* out = (float*)d_out;

  (void)hipFuncSetAttribute(reinterpret_cast<const void*>(draw_main),
                            hipFuncAttributeMaxDynamicSharedMemorySize, 49472);

  init_pack<<<5888, 256, 0, stream>>>(ih_mu, whh_mu, bih_mu, bhh_mu,
                                      ih_lv, whh_lv, bih_lv, bhh_lv,
                                      wmu, bmu, wlv, blv,
                                      wih_dec, whh_dec, bih_dec, bhh_dec,
                                      wwrite, bwrite, wsb);
  init_p2<<<512, 512, 0, stream>>>(x, wsb);
  draw_main<<<768, 512, 49472, stream>>>(noise, wsb, out);
}

// Round 7
// 5636.638 us; speedup vs baseline: 1.2108x; 1.2108x over previous
//
#include <hip/hip_runtime.h>
#include <cstdint>

typedef short bf16x8 __attribute__((ext_vector_type(8)));
typedef float f32x4 __attribute__((ext_vector_type(4)));

#define MFMA(a,b,c) __builtin_amdgcn_mfma_f32_16x16x32_bf16((a),(b),(c),0,0,0)

// ---------------- ws layout (bytes) ----------------
constexpr int FR = 512;                          // bf16 elems per fragment (64 lanes x 8)
constexpr size_t OP2   = 0;                                  // P2 f32 [512rt][42nt][64][4]
constexpr size_t SZP2  = (size_t)512*42*256*4;               // 22,020,096
constexpr size_t OWSUM = OP2 + SZP2;                         // [25ks][42nt][512] bf16
constexpr size_t SZWSUM= (size_t)25*42*FR*2;
constexpr size_t OWEAM = OWSUM + SZWSUM;                     // enc A-side weights mu [28][21][512]
constexpr size_t SZWEA = (size_t)28*21*FR*2;
constexpr size_t OWEAL = OWEAM + SZWEA;
constexpr size_t OWEBM = OWEAL + SZWEA;                      // enc h-side [4][21][512]
constexpr size_t SZWEB = (size_t)4*21*FR*2;
constexpr size_t OWEBL = OWEBM + SZWEB;
constexpr size_t OWH   = OWEBL + SZWEB;                      // heads [8][14][512]
constexpr size_t SZWH  = (size_t)8*14*FR*2;
constexpr size_t OWD   = OWH + SZWH;                         // dec [8][21][512]
constexpr size_t SZWD  = (size_t)8*21*FR*2;
constexpr size_t OWW   = OWD + SZWD;                         // write [4][49][512]
constexpr size_t SZWW  = (size_t)4*49*FR*2;
constexpr size_t OBP2  = OWW + SZWW;                         // f32 bias frags
constexpr size_t OBGHN = OBP2 + (size_t)42*256*4;
constexpr size_t OBDI  = OBGHN + (size_t)2*7*256*4;
constexpr size_t OBDHN = OBDI + (size_t)21*256*4;
constexpr size_t OBWR  = OBDHN + (size_t)7*256*4;
constexpr size_t OBH   = OBWR + (size_t)49*256*4;            // end ~25.1 MB

__device__ __forceinline__ float sigf(float x){ return 1.0f/(1.0f+__expf(-x)); }
__device__ __forceinline__ float tanhfast(float x){ return 1.0f - 2.0f/(__expf(2.0f*x)+1.0f); }
__device__ __forceinline__ float bf2f(unsigned short u){ return __uint_as_float(((unsigned int)u)<<16); }
__device__ __forceinline__ unsigned short f2bf(float f){ unsigned int x = __float_as_uint(f); return (unsigned short)((x + 0x8000u) >> 16); }

// ---------------- weight / bias fragment packing ----------------
__global__ void init_pack(
    const float* __restrict__ ihmu, const float* __restrict__ whhmu,
    const float* __restrict__ bihmu, const float* __restrict__ bhhmu,
    const float* __restrict__ ihlv, const float* __restrict__ whhlv,
    const float* __restrict__ bihlv, const float* __restrict__ bhhlv,
    const float* __restrict__ wmu, const float* __restrict__ bmu,
    const float* __restrict__ wlv, const float* __restrict__ blv,
    const float* __restrict__ ihd, const float* __restrict__ whhd,
    const float* __restrict__ bihd, const float* __restrict__ bhhd,
    const float* __restrict__ wwr, const float* __restrict__ bwr,
    char* __restrict__ wsb)
{
  int u = blockIdx.x*256 + threadIdx.x;
  if (u < 1469440) {
    int v = u; size_t off; int NT; int region;
    if      (v < 537600)            { region=0; off=OWSUM; NT=42; }
    else if ((v-=537600) < 301056)  { region=1; off=OWEAM; NT=21; }
    else if ((v-=301056) < 301056)  { region=2; off=OWEAL; NT=21; }
    else if ((v-=301056) < 43008)   { region=3; off=OWEBM; NT=21; }
    else if ((v-=43008)  < 43008)   { region=4; off=OWEBL; NT=21; }
    else if ((v-=43008)  < 57344)   { region=5; off=OWH;   NT=14; }
    else if ((v-=57344)  < 86016)   { region=6; off=OWD;   NT=21; }
    else    { v-=86016;   region=7; off=OWW;   NT=49; }
    int ks = v / (NT*512); int rem = v - ks*(NT*512);
    int nt = rem >> 9; int li = rem & 511;
    int l = li >> 3, e = li & 7;
    int k = ks*32 + ((l>>4)<<3) + e;
    int c = l & 15;
    float val = 0.f;
    if (region==0) {
      int gru = nt/21, ntg = nt%21, gate = ntg/7, j = (ntg%7)*16 + c;
      if (j<100 && k<784) { const float* IH = gru? ihlv : ihmu; int jj = gate*100+j;
        val = IH[(size_t)jj*1668 + k] + IH[(size_t)jj*1668 + 784 + k]; }
    } else if (region==1 || region==2) {
      const float* IH = (region==2)? ihlv : ihmu;
      int gate = nt/7, j = (nt%7)*16 + c;
      if (j<100) { int jj = gate*100+j;
        if (k<784)      val = -IH[(size_t)jj*1668 + 784 + k];
        else if (k<884) val =  IH[(size_t)jj*1668 + 1568 + (k-784)]; }
    } else if (region==3 || region==4) {
      const float* WHH = (region==4)? whhlv : whhmu;
      int gate = nt/7, j = (nt%7)*16 + c;
      if (j<100 && k<100) val = WHH[(gate*100+j)*100 + k];
    } else if (region==5) {
      int grp = nt/7, j = (nt%7)*16 + c;
      if (j<100) {
        if (grp==0) { if (k<100) val = wmu[j*100+k]; }
        else        { if (k>=128 && k<228) val = wlv[j*100 + (k-128)]; }
      }
    } else if (region==6) {
      int gate = nt/7, j = (nt%7)*16 + c;
      if (j<100) { int jj = gate*100+j;
        if (k<100)               val = ihd[jj*100+k];
        else if (k>=128 && k<228) val = whhd[jj*100 + (k-128)]; }
    } else {
      int n = nt*16 + c;
      if (k<100) val = wwr[n*100+k];
    }
    *(unsigned short*)(wsb + off + (size_t)v*2) = f2bf(val);
    return;
  }
  u -= 1469440;
  if (u >= 37632) return;
  float val = 0.f; size_t off; int v = u;
  if (v < 10752) { off = OBP2;
    int nt = v>>8, li = v&255, l = li>>2, c = l&15;
    int gru = nt/21, ntg = nt%21, gate = ntg/7, j = (ntg%7)*16 + c;
    if (j<100) {
      const float* BI = gru? bihlv : bihmu; const float* BH = gru? bhhlv : bhhmu;
      val = BI[gate*100+j] + ((gate<2)? BH[gate*100+j] : 0.f);
    }
  } else if ((v-=10752) < 3584) { off = OBGHN;
    int g = v/1792, r2 = v - g*1792, p = r2>>8, li = r2&255, l = li>>2, c = l&15;
    int j = p*16+c;
    if (j<100) val = (g? bhhlv : bhhmu)[200+j];
  } else if ((v-=3584) < 5376) { off = OBDI;
    int nt = v>>8, li = v&255, l = li>>2, c = l&15;
    int gate = nt/7, j = (nt%7)*16+c;
    if (j<100) val = (gate<2)? (bihd[gate*100+j]+bhhd[gate*100+j]) : bihd[200+j];
  } else if ((v-=5376) < 1792) { off = OBDHN;
    int p = v>>8, li = v&255, l = li>>2, c = l&15; int j = p*16+c;
    if (j<100) val = bhhd[200+j];
  } else if ((v-=1792) < 12544) { off = OBWR;
    int nt = v>>8, li = v&255, l = li>>2, c = l&15;
    val = bwr[nt*16+c];
  } else { v -= 12544; off = OBH;
    int nt = v>>8, li = v&255, l = li>>2, c = l&15;
    int grp = nt/7, j = (nt%7)*16+c;
    if (j<100) val = grp? blv[j] : bmu[j];
  }
  *(float*)(wsb + off + (size_t)v*4) = val;
}

// ---------------- P2 = x@(W1+W2)^T + bias, fragment-packed f32 ----------------
__global__ __launch_bounds__(512) void init_p2(const float* __restrict__ x, char* __restrict__ wsb)
{
  __shared__ char xt[16*1600];
  const int tid = threadIdx.x, l = tid&63, w = tid>>6;
  const int lr = l&15, lg = l>>4;
  const int rt = blockIdx.x;
  for (int i = tid; i < 16*800; i += 512) {
    int row = i/800, col = i - row*800;
    unsigned short hv = 0;
    if (col < 784) hv = f2bf(x[(size_t)(rt*16+row)*784 + col]);
    *(unsigned short*)(xt + ((row*1600 + col*2) ^ ((row&7)<<4))) = hv;
  }
  __syncthreads();
  const char* WS = wsb + OWSUM;
  for (int nt = w; nt < 42; nt += 8) {
    f32x4 acc = *(const f32x4*)(wsb + OBP2 + (size_t)(nt*256 + l*4)*4);
    const char* wp = WS + (size_t)(nt*512 + l*8)*2;
    #pragma unroll 5
    for (int ks = 0; ks < 25; ++ks) {
      bf16x8 a = *(const bf16x8*)(xt + ((lr*1600 + ks*64 + lg*16) ^ ((lr&7)<<4)));
      bf16x8 b = *(const bf16x8*)(wp + (size_t)ks*42*512*2);
      acc = MFMA(a,b,acc);
    }
    *(f32x4*)(wsb + OP2 + ((size_t)(rt*42+nt)*64 + l)*16) = acc;
  }
}

// ---------------- main persistent kernel: 512 blocks x 16 rows, 3 blk/CU ----------------
__global__ __launch_bounds__(512,6) void draw_main(
    const float* __restrict__ noise, const char* __restrict__ wsb, float* __restrict__ out)
{
  extern __shared__ char sm[];
  char* Aenc = sm;               // [16][1792 B] bf16: sigc(784) | hdec(100) | pad
  char* Ahml = sm + 28672;       // [16][512 B]  bf16: hmu(100) pad | hlv(100) pad
  char* Adec = sm + 36864;       // [16][512 B]  bf16: z(100) pad | hdec(100) pad
  unsigned short* muv16 = (unsigned short*)(sm + 45056);  // [16][100] mu | [16][100] lv bf16

  const int tid = threadIdx.x, l = tid&63, w = tid>>6;
  const int lr = l&15, lg = l>>4;
  const int blk = blockIdx.x;

  float* out_c  = out;
  float* out_mu = out + (size_t)8192*784;
  float* out_lv = out_mu + (size_t)32*8192*100;

  for (int i = tid; i < 16*896; i += 512) {
    int row = i/896, col = i - row*896;
    unsigned short v = (col<784)? (unsigned short)0x3F00 : (unsigned short)0;
    *(unsigned short*)(Aenc + ((row*1792 + col*2) ^ ((row&7)<<4))) = v;
  }
  for (int i = tid; i < 16*256; i += 512) {
    int row = i>>8, col = i&255;
    int a = (row*512 + col*2) ^ ((row&7)<<4);
    *(unsigned short*)(Ahml + a) = 0;
    *(unsigned short*)(Adec + a) = 0;
  }

  // per-wave job constants
  const int pm = w;            const bool actm = pm < 7;
  const int plv = (w+2)&7;     const bool actl = plv < 7;
  const int pd  = (w+4)&7;     const bool actd = pd < 7;
  const int axor = (lr&7)<<4;

  // ---- hoist step-invariant fragments into registers ----
  const f32x4 z4 = {0.f,0.f,0.f,0.f};
  f32x4 p2m[3] = {z4,z4,z4}, p2l[3] = {z4,z4,z4}, ahnm = z4, ahnl = z4;
  f32x4 dbr = z4, dbz = z4, dbn = z4, dbh = z4;
  if (actm) {
    size_t pb = OP2 + (((size_t)blk*42 + pm)*64 + l)*16;
    p2m[0] = *(const f32x4*)(wsb + pb);
    p2m[1] = *(const f32x4*)(wsb + pb + (size_t)7*64*16);
    p2m[2] = *(const f32x4*)(wsb + pb + (size_t)14*64*16);
    ahnm = *(const f32x4*)(wsb + OBGHN + (size_t)(pm*256 + l*4)*4);
  }
  if (actl) {
    size_t pb = OP2 + (((size_t)blk*42 + 21 + plv)*64 + l)*16;
    p2l[0] = *(const f32x4*)(wsb + pb);
    p2l[1] = *(const f32x4*)(wsb + pb + (size_t)7*64*16);
    p2l[2] = *(const f32x4*)(wsb + pb + (size_t)14*64*16);
    ahnl = *(const f32x4*)(wsb + OBGHN + (size_t)((7+plv)*256 + l*4)*4);
  }
  if (actd) {
    dbr = *(const f32x4*)(wsb + OBDI  + (size_t)(pd*256 + l*4)*4);
    dbz = *(const f32x4*)(wsb + OBDI  + (size_t)((pd+7)*256 + l*4)*4);
    dbn = *(const f32x4*)(wsb + OBDI  + (size_t)((pd+14)*256 + l*4)*4);
    dbh = *(const f32x4*)(wsb + OBDHN + (size_t)(pd*256 + l*4)*4);
  }

  f32x4 creg[7];
  #pragma unroll
  for (int q=0;q<7;++q) creg[q] = z4;
  f32x4 hm = z4, hl = z4, hd = z4;
  __syncthreads();

  for (int t = 0; t < 32; ++t) {
    // ---- noise prefetch (hides HBM latency under enc GEMM) ----
    float noz[4] = {0.f,0.f,0.f,0.f};
    if (w < 7) {
      int col = w*16 + lr;
      if (col < 100) {
        #pragma unroll
        for (int e=0;e<4;++e) {
          int row = lg*4 + e;
          noz[e] = __builtin_nontemporal_load(noise + (size_t)t*819200 + (size_t)(blk*16+row)*100 + col);
        }
      }
    }

    // ===== merged encoder GEMMs (mu + lv in one phase) =====
    f32x4 ar0=z4, az0=z4, an0=z4, ahn0=z4, ar1=z4, az1=z4, an1=z4, ahn1=z4;
    if (actm) { ar0 = p2m[0]; az0 = p2m[1]; an0 = p2m[2]; ahn0 = ahnm; }
    if (actl) { ar1 = p2l[0]; az1 = p2l[1]; an1 = p2l[2]; ahn1 = ahnl; }
    {
      const char* wr0 = wsb + OWEAM + (size_t)(pm*512 + l*8)*2;
      const char* wz0 = wr0 + (size_t)7*512*2;
      const char* wn0 = wr0 + (size_t)14*512*2;
      const char* wr1 = wsb + OWEAL + (size_t)(plv*512 + l*8)*2;
      const char* wz1 = wr1 + (size_t)7*512*2;
      const char* wn1 = wr1 + (size_t)14*512*2;
      int abase = lr*1792 + lg*16;
      #pragma unroll 4
      for (int ks=0; ks<28; ++ks) {
        bf16x8 a = *(const bf16x8*)(Aenc + ((abase + ks*64) ^ axor));
        size_t so = (size_t)ks*21*512*2;
        if (actm) {
          ar0 = MFMA(a, *(const bf16x8*)(wr0+so), ar0);
          az0 = MFMA(a, *(const bf16x8*)(wz0+so), az0);
          an0 = MFMA(a, *(const bf16x8*)(wn0+so), an0);
        }
        if (actl) {
          ar1 = MFMA(a, *(const bf16x8*)(wr1+so), ar1);
          az1 = MFMA(a, *(const bf16x8*)(wz1+so), az1);
          an1 = MFMA(a, *(const bf16x8*)(wn1+so), an1);
        }
      }
      const char* vr0 = wsb + OWEBM + (size_t)(pm*512 + l*8)*2;
      const char* vz0 = vr0 + (size_t)7*512*2;
      const char* vn0 = vr0 + (size_t)14*512*2;
      const char* vr1 = wsb + OWEBL + (size_t)(plv*512 + l*8)*2;
      const char* vz1 = vr1 + (size_t)7*512*2;
      const char* vn1 = vr1 + (size_t)14*512*2;
      int hb = lr*512 + lg*16;
      #pragma unroll
      for (int ks=0; ks<4; ++ks) {
        size_t so = (size_t)ks*21*512*2;
        if (actm) {
          bf16x8 a = *(const bf16x8*)(Ahml + ((hb + ks*64) ^ axor));
          ar0  = MFMA(a, *(const bf16x8*)(vr0+so), ar0);
          az0  = MFMA(a, *(const bf16x8*)(vz0+so), az0);
          ahn0 = MFMA(a, *(const bf16x8*)(vn0+so), ahn0);
        }
        if (actl) {
          bf16x8 a = *(const bf16x8*)(Ahml + ((hb + 256 + ks*64) ^ axor));
          ar1  = MFMA(a, *(const bf16x8*)(vr1+so), ar1);
          az1  = MFMA(a, *(const bf16x8*)(vz1+so), az1);
          ahn1 = MFMA(a, *(const bf16x8*)(vn1+so), ahn1);
        }
      }
    }
    __syncthreads();                       // B1: all Ahml reads done
    if (actm) {
      int col = pm*16 + lr;
      #pragma unroll
      for (int e=0;e<4;++e) {
        float rg = sigf(ar0[e]);
        float zg = sigf(az0[e]);
        float nn = tanhfast(fmaf(rg, ahn0[e], an0[e]));
        float hnew = nn + zg*(hm[e] - nn);
        hm[e] = hnew;
        if (col < 100) {
          int row = lg*4 + e;
          *(unsigned short*)(Ahml + ((row*512 + col*2) ^ ((row&7)<<4))) = f2bf(hnew);
        }
      }
    }
    if (actl) {
      int col = plv*16 + lr;
      #pragma unroll
      for (int e=0;e<4;++e) {
        float rg = sigf(ar1[e]);
        float zg = sigf(az1[e]);
        float nn = tanhfast(fmaf(rg, ahn1[e], an1[e]));
        float hnew = nn + zg*(hl[e] - nn);
        hl[e] = hnew;
        if (col < 100) {
          int row = lg*4 + e;
          *(unsigned short*)(Ahml + ((row*512 + (128+col)*2) ^ ((row&7)<<4))) = f2bf(hnew);
        }
      }
    }
    __syncthreads();                       // B2: hmu/hlv ready

    // ===== heads + reparameterize =====
    if (w < 7) {
      int p = w;
      int col = p*16 + lr;
      f32x4 am = *(const f32x4*)(wsb + OBH + (size_t)(p*256 + l*4)*4);
      f32x4 al = *(const f32x4*)(wsb + OBH + (size_t)((7+p)*256 + l*4)*4);
      const char* WH = wsb + OWH;
      int hb = lr*512 + lg*16;
      #pragma unroll
      for (int ks=0; ks<4; ++ks) {
        bf16x8 a0 = *(const bf16x8*)(Ahml + ((hb + ks*64) ^ axor));
        bf16x8 a1 = *(const bf16x8*)(Ahml + ((hb + 256 + ks*64) ^ axor));
        am = MFMA(a0, *(const bf16x8*)(WH + ((size_t)(ks*14+p)*512 + l*8)*2), am);
        al = MFMA(a1, *(const bf16x8*)(WH + ((size_t)((ks+4)*14+7+p)*512 + l*8)*2), al);
      }
      if (col < 100) {
        #pragma unroll
        for (int e=0;e<4;++e) {
          int row = lg*4 + e;
          float m  = fmaxf(am[e], 0.f);
          float lv = fmaxf(al[e], 0.f);
          muv16[row*100 + col]        = f2bf(m);
          muv16[1600 + row*100 + col] = f2bf(lv);
          float zz = fmaf(noz[e], __expf(0.5f*lv), m);
          *(unsigned short*)(Adec + ((row*512 + col*2) ^ ((row&7)<<4))) = f2bf(zz);
        }
      }
    }
    __syncthreads();                       // B3: muv + z ready

    // ===== dense NT store of mu/lv + decoder GRU gates =====
    {
      size_t mb = (size_t)t*819200 + (size_t)blk*1600;
      for (int i = tid; i < 800; i += 512) {
        bool isMu = (i < 400);
        int k = isMu ? i : i - 400;
        int off = (isMu ? 0 : 1600) + k*4;
        f32x4 v;
        #pragma unroll
        for (int j2=0;j2<4;++j2) v[j2] = bf2f(muv16[off + j2]);
        __builtin_nontemporal_store(v, (f32x4*)((isMu ? out_mu : out_lv) + mb) + k);
      }
      f32x4 dr=z4, dz=z4, dn=z4, dhn=z4;
      if (actd) {
        dr = dbr; dz = dbz; dn = dbn; dhn = dbh;
        const char* br = wsb + OWD + (size_t)(pd*512 + l*8)*2;
        const char* bz = br + (size_t)7*512*2;
        const char* bn = br + (size_t)14*512*2;
        int abase = lr*512 + lg*16;
        #pragma unroll
        for (int ks=0; ks<8; ++ks) {
          bf16x8 a = *(const bf16x8*)(Adec + ((abase + ks*64) ^ axor));
          size_t so = (size_t)ks*21*512*2;
          dr = MFMA(a, *(const bf16x8*)(br+so), dr);
          dz = MFMA(a, *(const bf16x8*)(bz+so), dz);
          if (ks<4) dn  = MFMA(a, *(const bf16x8*)(bn+so), dn);
          else      dhn = MFMA(a, *(const bf16x8*)(bn+so), dhn);
        }
      }
      __syncthreads();                     // B4: all Adec reads done
      if (actd) {
        int col = pd*16 + lr;
        #pragma unroll
        for (int e=0;e<4;++e) {
          float rg = sigf(dr[e]);
          float zg = sigf(dz[e]);
          float nn = tanhfast(fmaf(rg, dhn[e], dn[e]));
          float hnew = nn + zg*(hd[e] - nn);
          hd[e] = hnew;
          if (col < 100) {
            int row = lg*4 + e;
            unsigned short hb2 = f2bf(hnew);
            *(unsigned short*)(Adec + ((row*512 + (128+col)*2) ^ ((row&7)<<4))) = hb2;
            *(unsigned short*)(Aenc + ((row*1792 + (784+col)*2) ^ ((row&7)<<4))) = hb2;
          }
        }
      }
    }
    __syncthreads();                       // B5: new hdec visible

    // ===== canvas write GEMM: c += hdec @ Wwrite^T + bwrite =====
    {
      const char* WW = wsb + OWW;
      #pragma unroll
      for (int rep=0; rep<7; ++rep) {
        int nt = w + rep*8;
        if (nt < 49) {
          f32x4 c = creg[rep];
          int abase = lr*512 + 256 + lg*16;
          #pragma unroll
          for (int ks=0; ks<4; ++ks) {
            bf16x8 a = *(const bf16x8*)(Adec + ((abase + ks*64) ^ axor));
            c = MFMA(a, *(const bf16x8*)(WW + ((size_t)(ks*49+nt)*512 + l*8)*2), c);
          }
          f32x4 bw = *(const f32x4*)(wsb + OBWR + (size_t)(nt*256 + l*4)*4);
          c = c + bw;
          creg[rep] = c;
          #pragma unroll
          for (int e=0;e<4;++e) {
            float s = sigf(c[e]);
            int orow = lg*4 + e;
            int col = nt*16 + lr;
            if (t < 31) {
              *(unsigned short*)(Aenc + ((orow*1792 + col*2) ^ ((orow&7)<<4))) = f2bf(s);
            } else {
              __builtin_nontemporal_store(s, out_c + (size_t)(blk*16+orow)*784 + col);
            }
          }
        }
      }
    }
    __syncthreads();                       // B6: sigc ready for next step
  }
}

extern "C" void kernel_launch(void* const* d_in, const int* in_sizes, int n_in,
                              void* d_out, int out_size, void* d_ws, size_t ws_size,
                              hipStream_t stream) {
  (void)in_sizes; (void)n_in; (void)out_size; (void)ws_size;
  const float* x      = (const float*)d_in[0];
  const float* noise  = (const float*)d_in[1];
  const float* ih_mu  = (const float*)d_in[2];
  const float* whh_mu = (const float*)d_in[3];
  const float* bih_mu = (const float*)d_in[4];
  const float* bhh_mu = (const float*)d_in[5];
  const float* ih_lv  = (const float*)d_in[6];
  const float* whh_lv = (const float*)d_in[7];
  const float* bih_lv = (const float*)d_in[8];
  const float* bhh_lv = (const float*)d_in[9];
  const float* wmu    = (const float*)d_in[10];
  const float* bmu    = (const float*)d_in[11];
  const float* wlv    = (const float*)d_in[12];
  const float* blv    = (const float*)d_in[13];
  const float* wih_dec= (const float*)d_in[14];
  const float* whh_dec= (const float*)d_in[15];
  const float* bih_dec= (const float*)d_in[16];
  const float* bhh_dec= (const float*)d_in[17];
  const float* wwrite = (const float*)d_in[18];
  const float* bwrite = (const float*)d_in[19];
  char* wsb = (char*)d_ws;
  float* out = (float*)d_out;

  (void)hipFuncSetAttribute(reinterpret_cast<const void*>(draw_main),
                            hipFuncAttributeMaxDynamicSharedMemorySize, 51456);

  init_pack<<<5888, 256, 0, stream>>>(ih_mu, whh_mu, bih_mu, bhh_mu,
                                      ih_lv, whh_lv, bih_lv, bhh_lv,
                                      wmu, bmu, wlv, blv,
                                      wih_dec, whh_dec, bih_dec, bhh_dec,
                                      wwrite, bwrite, wsb);
  init_p2<<<512, 512, 0, stream>>>(x, wsb);
  draw_main<<<512, 512, 51456, stream>>>(noise, wsb, out);
}

// Round 8
// 3999.031 us; speedup vs baseline: 1.7067x; 1.4095x over previous
//
#include <hip/hip_runtime.h>
#include <cstdint>

typedef short bf16x8 __attribute__((ext_vector_type(8)));
typedef float f32x4 __attribute__((ext_vector_type(4)));

#define MFMA(a,b,c) __builtin_amdgcn_mfma_f32_16x16x32_bf16((a),(b),(c),0,0,0)

// ---------------- ws layout (bytes) ----------------
constexpr int FR = 512;                          // bf16 elems per fragment (64 lanes x 8)
constexpr size_t OP2   = 0;                                  // P2 f32 [512rt][42nt][64][4]
constexpr size_t SZP2  = (size_t)512*42*256*4;               // 22,020,096
constexpr size_t OWSUM = OP2 + SZP2;                         // [25ks][42nt][512] bf16
constexpr size_t SZWSUM= (size_t)25*42*FR*2;
constexpr size_t OWEAM = OWSUM + SZWSUM;                     // enc A-side weights mu [28][21][512]
constexpr size_t SZWEA = (size_t)28*21*FR*2;
constexpr size_t OWEAL = OWEAM + SZWEA;
constexpr size_t OWEBM = OWEAL + SZWEA;                      // enc h-side [4][21][512]
constexpr size_t SZWEB = (size_t)4*21*FR*2;
constexpr size_t OWEBL = OWEBM + SZWEB;
constexpr size_t OWH   = OWEBL + SZWEB;                      // heads [8][14][512]
constexpr size_t SZWH  = (size_t)8*14*FR*2;
constexpr size_t OWD   = OWH + SZWH;                         // dec [8][21][512]
constexpr size_t SZWD  = (size_t)8*21*FR*2;
constexpr size_t OWW   = OWD + SZWD;                         // write [4][49][512]
constexpr size_t SZWW  = (size_t)4*49*FR*2;
constexpr size_t OBP2  = OWW + SZWW;                         // f32 bias frags
constexpr size_t OBGHN = OBP2 + (size_t)42*256*4;
constexpr size_t OBDI  = OBGHN + (size_t)2*7*256*4;
constexpr size_t OBDHN = OBDI + (size_t)21*256*4;
constexpr size_t OBWR  = OBDHN + (size_t)7*256*4;
constexpr size_t OBH   = OBWR + (size_t)49*256*4;            // end ~25.1 MB

__device__ __forceinline__ float sigf(float x){ return 1.0f/(1.0f+__expf(-x)); }
__device__ __forceinline__ float tanhfast(float x){ return 1.0f - 2.0f/(__expf(2.0f*x)+1.0f); }
__device__ __forceinline__ float bf2f(unsigned short u){ return __uint_as_float(((unsigned int)u)<<16); }
__device__ __forceinline__ unsigned short f2bf(float f){ unsigned int x = __float_as_uint(f); return (unsigned short)((x + 0x8000u) >> 16); }

// ---------------- weight / bias fragment packing ----------------
__global__ void init_pack(
    const float* __restrict__ ihmu, const float* __restrict__ whhmu,
    const float* __restrict__ bihmu, const float* __restrict__ bhhmu,
    const float* __restrict__ ihlv, const float* __restrict__ whhlv,
    const float* __restrict__ bihlv, const float* __restrict__ bhhlv,
    const float* __restrict__ wmu, const float* __restrict__ bmu,
    const float* __restrict__ wlv, const float* __restrict__ blv,
    const float* __restrict__ ihd, const float* __restrict__ whhd,
    const float* __restrict__ bihd, const float* __restrict__ bhhd,
    const float* __restrict__ wwr, const float* __restrict__ bwr,
    char* __restrict__ wsb)
{
  int u = blockIdx.x*256 + threadIdx.x;
  if (u < 1469440) {
    int v = u; size_t off; int NT; int region;
    if      (v < 537600)            { region=0; off=OWSUM; NT=42; }
    else if ((v-=537600) < 301056)  { region=1; off=OWEAM; NT=21; }
    else if ((v-=301056) < 301056)  { region=2; off=OWEAL; NT=21; }
    else if ((v-=301056) < 43008)   { region=3; off=OWEBM; NT=21; }
    else if ((v-=43008)  < 43008)   { region=4; off=OWEBL; NT=21; }
    else if ((v-=43008)  < 57344)   { region=5; off=OWH;   NT=14; }
    else if ((v-=57344)  < 86016)   { region=6; off=OWD;   NT=21; }
    else    { v-=86016;   region=7; off=OWW;   NT=49; }
    int ks = v / (NT*512); int rem = v - ks*(NT*512);
    int nt = rem >> 9; int li = rem & 511;
    int l = li >> 3, e = li & 7;
    int k = ks*32 + ((l>>4)<<3) + e;
    int c = l & 15;
    float val = 0.f;
    if (region==0) {
      int gru = nt/21, ntg = nt%21, gate = ntg/7, j = (ntg%7)*16 + c;
      if (j<100 && k<784) { const float* IH = gru? ihlv : ihmu; int jj = gate*100+j;
        val = IH[(size_t)jj*1668 + k] + IH[(size_t)jj*1668 + 784 + k]; }
    } else if (region==1 || region==2) {
      const float* IH = (region==2)? ihlv : ihmu;
      int gate = nt/7, j = (nt%7)*16 + c;
      if (j<100) { int jj = gate*100+j;
        if (k<784)      val = -IH[(size_t)jj*1668 + 784 + k];
        else if (k<884) val =  IH[(size_t)jj*1668 + 1568 + (k-784)]; }
    } else if (region==3 || region==4) {
      const float* WHH = (region==4)? whhlv : whhmu;
      int gate = nt/7, j = (nt%7)*16 + c;
      if (j<100 && k<100) val = WHH[(gate*100+j)*100 + k];
    } else if (region==5) {
      int grp = nt/7, j = (nt%7)*16 + c;
      if (j<100) {
        if (grp==0) { if (k<100) val = wmu[j*100+k]; }
        else        { if (k>=128 && k<228) val = wlv[j*100 + (k-128)]; }
      }
    } else if (region==6) {
      int gate = nt/7, j = (nt%7)*16 + c;
      if (j<100) { int jj = gate*100+j;
        if (k<100)               val = ihd[jj*100+k];
        else if (k>=128 && k<228) val = whhd[jj*100 + (k-128)]; }
    } else {
      int n = nt*16 + c;
      if (k<100) val = wwr[n*100+k];
    }
    *(unsigned short*)(wsb + off + (size_t)v*2) = f2bf(val);
    return;
  }
  u -= 1469440;
  if (u >= 37632) return;
  float val = 0.f; size_t off; int v = u;
  if (v < 10752) { off = OBP2;
    int nt = v>>8, li = v&255, l = li>>2, c = l&15;
    int gru = nt/21, ntg = nt%21, gate = ntg/7, j = (ntg%7)*16 + c;
    if (j<100) {
      const float* BI = gru? bihlv : bihmu; const float* BH = gru? bhhlv : bhhmu;
      val = BI[gate*100+j] + ((gate<2)? BH[gate*100+j] : 0.f);
    }
  } else if ((v-=10752) < 3584) { off = OBGHN;
    int g = v/1792, r2 = v - g*1792, p = r2>>8, li = r2&255, l = li>>2, c = l&15;
    int j = p*16+c;
    if (j<100) val = (g? bhhlv : bhhmu)[200+j];
  } else if ((v-=3584) < 5376) { off = OBDI;
    int nt = v>>8, li = v&255, l = li>>2, c = l&15;
    int gate = nt/7, j = (nt%7)*16+c;
    if (j<100) val = (gate<2)? (bihd[gate*100+j]+bhhd[gate*100+j]) : bihd[200+j];
  } else if ((v-=5376) < 1792) { off = OBDHN;
    int p = v>>8, li = v&255, l = li>>2, c = l&15; int j = p*16+c;
    if (j<100) val = bhhd[200+j];
  } else if ((v-=1792) < 12544) { off = OBWR;
    int nt = v>>8, li = v&255, l = li>>2, c = l&15;
    val = bwr[nt*16+c];
  } else { v -= 12544; off = OBH;
    int nt = v>>8, li = v&255, l = li>>2, c = l&15;
    int grp = nt/7, j = (nt%7)*16+c;
    if (j<100) val = grp? blv[j] : bmu[j];
  }
  *(float*)(wsb + off + (size_t)v*4) = val;
}

// ---------------- P2 = x@(W1+W2)^T + bias, fragment-packed f32 ----------------
__global__ __launch_bounds__(512) void init_p2(const float* __restrict__ x, char* __restrict__ wsb)
{
  __shared__ char xt[16*1600];
  const int tid = threadIdx.x, l = tid&63, w = tid>>6;
  const int lr = l&15, lg = l>>4;
  const int rt = blockIdx.x;
  for (int i = tid; i < 16*800; i += 512) {
    int row = i/800, col = i - row*800;
    unsigned short hv = 0;
    if (col < 784) hv = f2bf(x[(size_t)(rt*16+row)*784 + col]);
    *(unsigned short*)(xt + ((row*1600 + col*2) ^ ((row&7)<<4))) = hv;
  }
  __syncthreads();
  const char* WS = wsb + OWSUM;
  for (int nt = w; nt < 42; nt += 8) {
    f32x4 acc = *(const f32x4*)(wsb + OBP2 + (size_t)(nt*256 + l*4)*4);
    const char* wp = WS + (size_t)(nt*512 + l*8)*2;
    #pragma unroll 5
    for (int ks = 0; ks < 25; ++ks) {
      bf16x8 a = *(const bf16x8*)(xt + ((lr*1600 + ks*64 + lg*16) ^ ((lr&7)<<4)));
      bf16x8 b = *(const bf16x8*)(wp + (size_t)ks*42*512*2);
      acc = MFMA(a,b,acc);
    }
    *(f32x4*)(wsb + OP2 + ((size_t)(rt*42+nt)*64 + l)*16) = acc;
  }
}

// ------- main persistent kernel: 512 blocks x 1024 threads (16 waves), 16 rows -------
__global__ __launch_bounds__(1024,8) void draw_main(
    const float* __restrict__ noise, const char* __restrict__ wsb, float* __restrict__ out)
{
  extern __shared__ char sm[];
  char* Aenc = sm;               // [16][1792 B] bf16: sigc(784) | hdec(100) | pad
  char* Ahml = sm + 28672;       // [16][512 B]  bf16: hmu(100) pad | hlv(100) pad
  char* Adec = sm + 36864;       // [16][512 B]  bf16: z(100) pad | hdec(100) pad
  unsigned short* muv16 = (unsigned short*)(sm + 45056);  // [1600] mu | [1600] lv bf16

  const int tid = threadIdx.x, l = tid&63, w = tid>>6;   // w in [0,16)
  const int lr = l&15, lg = l>>4;
  const int blk = blockIdx.x;

  float* out_c  = out;
  float* out_mu = out + (size_t)8192*784;
  float* out_lv = out_mu + (size_t)32*8192*100;

  for (int i = tid; i < 16*896; i += 1024) {
    int row = i/896, col = i - row*896;
    unsigned short v = (col<784)? (unsigned short)0x3F00 : (unsigned short)0;
    *(unsigned short*)(Aenc + ((row*1792 + col*2) ^ ((row&7)<<4))) = v;
  }
  for (int i = tid; i < 16*256; i += 1024) {
    int row = i>>8, col = i&255;
    int a = (row*512 + col*2) ^ ((row&7)<<4);
    *(unsigned short*)(Ahml + a) = 0;
    *(unsigned short*)(Adec + a) = 0;
  }

  // wave roles: 0-6 = mu path, 8-14 = lv+dec path, 7/15 = helper (z/store/write only)
  const bool isMu = (w < 7);
  const bool isLv = (w >= 8 && w < 15);
  const bool act  = isMu || isLv;
  const int p = isMu ? w : (w - 8);
  const int axor = (lr&7)<<4;

  const f32x4 z4 = {0.f,0.f,0.f,0.f};
  f32x4 p2j[3] = {z4,z4,z4};
  if (act) {
    size_t pb = OP2 + (((size_t)blk*42 + (isLv?21:0) + p)*64 + l)*16;
    p2j[0] = *(const f32x4*)(wsb + pb);
    p2j[1] = *(const f32x4*)(wsb + pb + (size_t)7*64*16);
    p2j[2] = *(const f32x4*)(wsb + pb + (size_t)14*64*16);
  }
  f32x4 creg[4] = {z4,z4,z4,z4};
  f32x4 hreg = z4;   // hm (mu waves) / hl (lv waves)
  f32x4 hd = z4;     // decoder state (lv waves)
  __syncthreads();

  for (int t = 0; t < 32; ++t) {
    // ---- noise prefetch: 1600 contiguous floats, fully coalesced ----
    float noz[2] = {0.f, 0.f};
    #pragma unroll
    for (int k2=0;k2<2;++k2) {
      int i = tid + k2*1024;
      if (i < 1600)
        noz[k2] = __builtin_nontemporal_load(noise + (size_t)t*819200 + (size_t)blk*1600 + i);
    }

    // ===== encoder GEMM (mu waves: OWEAM, lv waves: OWEAL) =====
    f32x4 ar=z4, az=z4, an=z4, ahn=z4;
    if (act) {
      ar = p2j[0]; az = p2j[1]; an = p2j[2];
      ahn = *(const f32x4*)(wsb + OBGHN + (size_t)(((isLv?7:0)+p)*256 + l*4)*4);
      const char* wr = wsb + (isLv? OWEAL : OWEAM) + (size_t)(p*512 + l*8)*2;
      const char* wz = wr + (size_t)7*512*2;
      const char* wn = wr + (size_t)14*512*2;
      int abase = lr*1792 + lg*16;
      #pragma unroll 4
      for (int ks=0; ks<28; ++ks) {
        bf16x8 a = *(const bf16x8*)(Aenc + ((abase + ks*64) ^ axor));
        size_t so = (size_t)ks*21*512*2;
        ar = MFMA(a, *(const bf16x8*)(wr+so), ar);
        az = MFMA(a, *(const bf16x8*)(wz+so), az);
        an = MFMA(a, *(const bf16x8*)(wn+so), an);
      }
      const char* vr = wsb + (isLv? OWEBL : OWEBM) + (size_t)(p*512 + l*8)*2;
      const char* vz = vr + (size_t)7*512*2;
      const char* vn = vr + (size_t)14*512*2;
      int hb = lr*512 + (isLv?256:0) + lg*16;
      #pragma unroll
      for (int ks=0; ks<4; ++ks) {
        bf16x8 a = *(const bf16x8*)(Ahml + ((hb + ks*64) ^ axor));
        size_t so = (size_t)ks*21*512*2;
        ar  = MFMA(a, *(const bf16x8*)(vr+so), ar);
        az  = MFMA(a, *(const bf16x8*)(vz+so), az);
        ahn = MFMA(a, *(const bf16x8*)(vn+so), ahn);
      }
    }
    __syncthreads();                       // B1: Ahml reads done
    if (act) {
      int col = p*16 + lr;
      #pragma unroll
      for (int e=0;e<4;++e) {
        float rg = sigf(ar[e]);
        float zg = sigf(az[e]);
        float nn = tanhfast(fmaf(rg, ahn[e], an[e]));
        float hnew = nn + zg*(hreg[e] - nn);
        hreg[e] = hnew;
        if (col < 100) {
          int row = lg*4 + e;
          *(unsigned short*)(Ahml + ((row*512 + ((isLv?128:0)+col)*2) ^ ((row&7)<<4))) = f2bf(hnew);
        }
      }
    }
    __syncthreads();                       // B2: hmu/hlv ready

    // ===== heads (mu waves -> mu, lv waves -> lv) =====
    if (isMu) {
      f32x4 am = *(const f32x4*)(wsb + OBH + (size_t)(p*256 + l*4)*4);
      const char* WH = wsb + OWH;
      int hb = lr*512 + lg*16;
      #pragma unroll
      for (int ks=0; ks<4; ++ks) {
        bf16x8 a0 = *(const bf16x8*)(Ahml + ((hb + ks*64) ^ axor));
        am = MFMA(a0, *(const bf16x8*)(WH + ((size_t)(ks*14+p)*512 + l*8)*2), am);
      }
      int col = p*16 + lr;
      if (col < 100) {
        #pragma unroll
        for (int e=0;e<4;++e)
          muv16[(lg*4+e)*100 + col] = f2bf(fmaxf(am[e], 0.f));
      }
    } else if (isLv) {
      f32x4 al = *(const f32x4*)(wsb + OBH + (size_t)((7+p)*256 + l*4)*4);
      const char* WH = wsb + OWH;
      int hb = lr*512 + 256 + lg*16;
      #pragma unroll
      for (int ks=0; ks<4; ++ks) {
        bf16x8 a1 = *(const bf16x8*)(Ahml + ((hb + ks*64) ^ axor));
        al = MFMA(a1, *(const bf16x8*)(WH + ((size_t)((ks+4)*14+7+p)*512 + l*8)*2), al);
      }
      int col = p*16 + lr;
      if (col < 100) {
        #pragma unroll
        for (int e=0;e<4;++e)
          muv16[1600 + (lg*4+e)*100 + col] = f2bf(fmaxf(al[e], 0.f));
      }
    }
    __syncthreads();                       // B3: muv16 complete

    // ===== z-compute (elementwise) + dense NT store of mu/lv =====
    #pragma unroll
    for (int k2=0;k2<2;++k2) {
      int i = tid + k2*1024;
      if (i < 1600) {
        float m  = bf2f(muv16[i]);
        float lv = bf2f(muv16[1600 + i]);
        float zz = fmaf(noz[k2], __expf(0.5f*lv), m);
        int row = i/100, col = i - row*100;
        *(unsigned short*)(Adec + ((row*512 + col*2) ^ ((row&7)<<4))) = f2bf(zz);
      }
    }
    {
      size_t mb = (size_t)t*819200 + (size_t)blk*1600;
      if (tid < 800) {
        bool m0 = tid < 400;
        int k = m0 ? tid : tid - 400;
        int off = (m0 ? 0 : 1600) + k*4;
        f32x4 v;
        #pragma unroll
        for (int j2=0;j2<4;++j2) v[j2] = bf2f(muv16[off + j2]);
        __builtin_nontemporal_store(v, (f32x4*)((m0 ? out_mu : out_lv) + mb) + k);
      }
    }
    __syncthreads();                       // B4: Adec z ready

    // ===== decoder GRU (lv waves) =====
    f32x4 dr=z4, dz=z4, dn=z4, dhn=z4;
    if (isLv) {
      dr  = *(const f32x4*)(wsb + OBDI  + (size_t)(p*256 + l*4)*4);
      dz  = *(const f32x4*)(wsb + OBDI  + (size_t)((p+7)*256 + l*4)*4);
      dn  = *(const f32x4*)(wsb + OBDI  + (size_t)((p+14)*256 + l*4)*4);
      dhn = *(const f32x4*)(wsb + OBDHN + (size_t)(p*256 + l*4)*4);
      const char* br = wsb + OWD + (size_t)(p*512 + l*8)*2;
      const char* bz = br + (size_t)7*512*2;
      const char* bn = br + (size_t)14*512*2;
      int abase = lr*512 + lg*16;
      #pragma unroll
      for (int ks=0; ks<8; ++ks) {
        bf16x8 a = *(const bf16x8*)(Adec + ((abase + ks*64) ^ axor));
        size_t so = (size_t)ks*21*512*2;
        dr = MFMA(a, *(const bf16x8*)(br+so), dr);
        dz = MFMA(a, *(const bf16x8*)(bz+so), dz);
        if (ks<4) dn  = MFMA(a, *(const bf16x8*)(bn+so), dn);
        else      dhn = MFMA(a, *(const bf16x8*)(bn+so), dhn);
      }
    }
    __syncthreads();                       // B5: Adec reads done
    if (isLv) {
      int col = p*16 + lr;
      #pragma unroll
      for (int e=0;e<4;++e) {
        float rg = sigf(dr[e]);
        float zg = sigf(dz[e]);
        float nn = tanhfast(fmaf(rg, dhn[e], dn[e]));
        float hnew = nn + zg*(hd[e] - nn);
        hd[e] = hnew;
        if (col < 100) {
          int row = lg*4 + e;
          unsigned short hb2 = f2bf(hnew);
          *(unsigned short*)(Adec + ((row*512 + (128+col)*2) ^ ((row&7)<<4))) = hb2;
          *(unsigned short*)(Aenc + ((row*1792 + (784+col)*2) ^ ((row&7)<<4))) = hb2;
        }
      }
    }
    __syncthreads();                       // B6: new hdec visible

    // ===== canvas write GEMM: all 16 waves, nt = w + 16*rep =====
    {
      const char* WW = wsb + OWW;
      #pragma unroll
      for (int rep=0; rep<4; ++rep) {
        int nt = w + rep*16;
        if (nt < 49) {
          f32x4 c = creg[rep];
          int abase = lr*512 + 256 + lg*16;
          #pragma unroll
          for (int ks=0; ks<4; ++ks) {
            bf16x8 a = *(const bf16x8*)(Adec + ((abase + ks*64) ^ axor));
            c = MFMA(a, *(const bf16x8*)(WW + ((size_t)(ks*49+nt)*512 + l*8)*2), c);
          }
          f32x4 bw = *(const f32x4*)(wsb + OBWR + (size_t)(nt*256 + l*4)*4);
          c = c + bw;
          creg[rep] = c;
          #pragma unroll
          for (int e=0;e<4;++e) {
            float s = sigf(c[e]);
            int orow = lg*4 + e;
            int col = nt*16 + lr;
            if (t < 31) {
              *(unsigned short*)(Aenc + ((orow*1792 + col*2) ^ ((orow&7)<<4))) = f2bf(s);
            } else {
              __builtin_nontemporal_store(s, out_c + (size_t)(blk*16+orow)*784 + col);
            }
          }
        }
      }
    }
    __syncthreads();                       // B7: sigc ready for next step
  }
}

extern "C" void kernel_launch(void* const* d_in, const int* in_sizes, int n_in,
                              void* d_out, int out_size, void* d_ws, size_t ws_size,
                              hipStream_t stream) {
  (void)in_sizes; (void)n_in; (void)out_size; (void)ws_size;
  const float* x      = (const float*)d_in[0];
  const float* noise  = (const float*)d_in[1];
  const float* ih_mu  = (const float*)d_in[2];
  const float* whh_mu = (const float*)d_in[3];
  const float* bih_mu = (const float*)d_in[4];
  const float* bhh_mu = (const float*)d_in[5];
  const float* ih_lv  = (const float*)d_in[6];
  const float* whh_lv = (const float*)d_in[7];
  const float* bih_lv = (const float*)d_in[8];
  const float* bhh_lv = (const float*)d_in[9];
  const float* wmu    = (const float*)d_in[10];
  const float* bmu    = (const float*)d_in[11];
  const float* wlv    = (const float*)d_in[12];
  const float* blv    = (const float*)d_in[13];
  const float* wih_dec= (const float*)d_in[14];
  const float* whh_dec= (const float*)d_in[15];
  const float* bih_dec= (const float*)d_in[16];
  const float* bhh_dec= (const float*)d_in[17];
  const float* wwrite = (const float*)d_in[18];
  const float* bwrite = (const float*)d_in[19];
  char* wsb = (char*)d_ws;
  float* out = (float*)d_out;

  (void)hipFuncSetAttribute(reinterpret_cast<const void*>(draw_main),
                            hipFuncAttributeMaxDynamicSharedMemorySize, 51456);

  init_pack<<<5888, 256, 0, stream>>>(ih_mu, whh_mu, bih_mu, bhh_mu,
                                      ih_lv, whh_lv, bih_lv, bhh_lv,
                                      wmu, bmu, wlv, blv,
                                      wih_dec, whh_dec, bih_dec, bhh_dec,
                                      wwrite, bwrite, wsb);
  init_p2<<<512, 512, 0, stream>>>(x, wsb);
  draw_main<<<512, 1024, 51456, stream>>>(noise, wsb, out);
}

// Round 9
// 3930.684 us; speedup vs baseline: 1.7363x; 1.0174x over previous
//
#include <hip/hip_runtime.h>
#include <cstdint>

typedef short bf16x8 __attribute__((ext_vector_type(8)));
typedef float f32x4 __attribute__((ext_vector_type(4)));

#define MFMA(a,b,c) __builtin_amdgcn_mfma_f32_16x16x32_bf16((a),(b),(c),0,0,0)

// ---------------- ws layout (bytes) ----------------
constexpr int FR = 512;                          // bf16 elems per fragment (64 lanes x 8)
constexpr size_t OP2   = 0;                                  // P2 f32 [512rt][42nt][64][4]
constexpr size_t SZP2  = (size_t)512*42*256*4;               // 22,020,096
constexpr size_t OWSUM = OP2 + SZP2;                         // [25ks][42nt][512] bf16
constexpr size_t SZWSUM= (size_t)25*42*FR*2;
constexpr size_t OWEAM = OWSUM + SZWSUM;                     // enc A-side weights mu [28][21][512]
constexpr size_t SZWEA = (size_t)28*21*FR*2;
constexpr size_t OWEAL = OWEAM + SZWEA;
constexpr size_t OWEBM = OWEAL + SZWEA;                      // enc h-side [4][21][512]
constexpr size_t SZWEB = (size_t)4*21*FR*2;
constexpr size_t OWEBL = OWEBM + SZWEB;
constexpr size_t OWH   = OWEBL + SZWEB;                      // heads [8][14][512]
constexpr size_t SZWH  = (size_t)8*14*FR*2;
constexpr size_t OWD   = OWH + SZWH;                         // dec [8][21][512]
constexpr size_t SZWD  = (size_t)8*21*FR*2;
constexpr size_t OWW   = OWD + SZWD;                         // write [4][49][512]
constexpr size_t SZWW  = (size_t)4*49*FR*2;
constexpr size_t OBP2  = OWW + SZWW;                         // f32 bias frags
constexpr size_t OBGHN = OBP2 + (size_t)42*256*4;
constexpr size_t OBDI  = OBGHN + (size_t)2*7*256*4;
constexpr size_t OBDHN = OBDI + (size_t)21*256*4;
constexpr size_t OBWR  = OBDHN + (size_t)7*256*4;
constexpr size_t OBH   = OBWR + (size_t)49*256*4;            // end ~25.1 MB

__device__ __forceinline__ float sigf(float x){ return 1.0f/(1.0f+__expf(-x)); }
__device__ __forceinline__ float tanhfast(float x){ return 1.0f - 2.0f/(__expf(2.0f*x)+1.0f); }
__device__ __forceinline__ float bf2f(unsigned short u){ return __uint_as_float(((unsigned int)u)<<16); }
__device__ __forceinline__ unsigned short f2bf(float f){ unsigned int x = __float_as_uint(f); return (unsigned short)((x + 0x8000u) >> 16); }

// ---------------- weight / bias fragment packing ----------------
__global__ void init_pack(
    const float* __restrict__ ihmu, const float* __restrict__ whhmu,
    const float* __restrict__ bihmu, const float* __restrict__ bhhmu,
    const float* __restrict__ ihlv, const float* __restrict__ whhlv,
    const float* __restrict__ bihlv, const float* __restrict__ bhhlv,
    const float* __restrict__ wmu, const float* __restrict__ bmu,
    const float* __restrict__ wlv, const float* __restrict__ blv,
    const float* __restrict__ ihd, const float* __restrict__ whhd,
    const float* __restrict__ bihd, const float* __restrict__ bhhd,
    const float* __restrict__ wwr, const float* __restrict__ bwr,
    char* __restrict__ wsb)
{
  int u = blockIdx.x*256 + threadIdx.x;
  if (u < 1469440) {
    int v = u; size_t off; int NT; int region;
    if      (v < 537600)            { region=0; off=OWSUM; NT=42; }
    else if ((v-=537600) < 301056)  { region=1; off=OWEAM; NT=21; }
    else if ((v-=301056) < 301056)  { region=2; off=OWEAL; NT=21; }
    else if ((v-=301056) < 43008)   { region=3; off=OWEBM; NT=21; }
    else if ((v-=43008)  < 43008)   { region=4; off=OWEBL; NT=21; }
    else if ((v-=43008)  < 57344)   { region=5; off=OWH;   NT=14; }
    else if ((v-=57344)  < 86016)   { region=6; off=OWD;   NT=21; }
    else    { v-=86016;   region=7; off=OWW;   NT=49; }
    int ks = v / (NT*512); int rem = v - ks*(NT*512);
    int nt = rem >> 9; int li = rem & 511;
    int l = li >> 3, e = li & 7;
    int k = ks*32 + ((l>>4)<<3) + e;
    int c = l & 15;
    float val = 0.f;
    if (region==0) {
      int gru = nt/21, ntg = nt%21, gate = ntg/7, j = (ntg%7)*16 + c;
      if (j<100 && k<784) { const float* IH = gru? ihlv : ihmu; int jj = gate*100+j;
        val = IH[(size_t)jj*1668 + k] + IH[(size_t)jj*1668 + 784 + k]; }
    } else if (region==1 || region==2) {
      const float* IH = (region==2)? ihlv : ihmu;
      int gate = nt/7, j = (nt%7)*16 + c;
      if (j<100) { int jj = gate*100+j;
        if (k<784)      val = -IH[(size_t)jj*1668 + 784 + k];
        else if (k<884) val =  IH[(size_t)jj*1668 + 1568 + (k-784)]; }
    } else if (region==3 || region==4) {
      const float* WHH = (region==4)? whhlv : whhmu;
      int gate = nt/7, j = (nt%7)*16 + c;
      if (j<100 && k<100) val = WHH[(gate*100+j)*100 + k];
    } else if (region==5) {
      int grp = nt/7, j = (nt%7)*16 + c;
      if (j<100) {
        if (grp==0) { if (k<100) val = wmu[j*100+k]; }
        else        { if (k>=128 && k<228) val = wlv[j*100 + (k-128)]; }
      }
    } else if (region==6) {
      int gate = nt/7, j = (nt%7)*16 + c;
      if (j<100) { int jj = gate*100+j;
        if (k<100)               val = ihd[jj*100+k];
        else if (k>=128 && k<228) val = whhd[jj*100 + (k-128)]; }
    } else {
      int n = nt*16 + c;
      if (k<100) val = wwr[n*100+k];
    }
    *(unsigned short*)(wsb + off + (size_t)v*2) = f2bf(val);
    return;
  }
  u -= 1469440;
  if (u >= 37632) return;
  float val = 0.f; size_t off; int v = u;
  if (v < 10752) { off = OBP2;
    int nt = v>>8, li = v&255, l = li>>2, c = l&15;
    int gru = nt/21, ntg = nt%21, gate = ntg/7, j = (ntg%7)*16 + c;
    if (j<100) {
      const float* BI = gru? bihlv : bihmu; const float* BH = gru? bhhlv : bhhmu;
      val = BI[gate*100+j] + ((gate<2)? BH[gate*100+j] : 0.f);
    }
  } else if ((v-=10752) < 3584) { off = OBGHN;
    int g = v/1792, r2 = v - g*1792, p = r2>>8, li = r2&255, l = li>>2, c = l&15;
    int j = p*16+c;
    if (j<100) val = (g? bhhlv : bhhmu)[200+j];
  } else if ((v-=3584) < 5376) { off = OBDI;
    int nt = v>>8, li = v&255, l = li>>2, c = l&15;
    int gate = nt/7, j = (nt%7)*16+c;
    if (j<100) val = (gate<2)? (bihd[gate*100+j]+bhhd[gate*100+j]) : bihd[200+j];
  } else if ((v-=5376) < 1792) { off = OBDHN;
    int p = v>>8, li = v&255, l = li>>2, c = l&15; int j = p*16+c;
    if (j<100) val = bhhd[200+j];
  } else if ((v-=1792) < 12544) { off = OBWR;
    int nt = v>>8, li = v&255, l = li>>2, c = l&15;
    val = bwr[nt*16+c];
  } else { v -= 12544; off = OBH;
    int nt = v>>8, li = v&255, l = li>>2, c = l&15;
    int grp = nt/7, j = (nt%7)*16+c;
    if (j<100) val = grp? blv[j] : bmu[j];
  }
  *(float*)(wsb + off + (size_t)v*4) = val;
}

// ---------------- P2 = x@(W1+W2)^T + bias, fragment-packed f32 ----------------
__global__ __launch_bounds__(512) void init_p2(const float* __restrict__ x, char* __restrict__ wsb)
{
  __shared__ char xt[16*1600];
  const int tid = threadIdx.x, l = tid&63, w = tid>>6;
  const int lr = l&15, lg = l>>4;
  const int rt = blockIdx.x;
  for (int i = tid; i < 16*800; i += 512) {
    int row = i/800, col = i - row*800;
    unsigned short hv = 0;
    if (col < 784) hv = f2bf(x[(size_t)(rt*16+row)*784 + col]);
    *(unsigned short*)(xt + ((row*1600 + col*2) ^ ((row&7)<<4))) = hv;
  }
  __syncthreads();
  const char* WS = wsb + OWSUM;
  for (int nt = w; nt < 42; nt += 8) {
    f32x4 acc = *(const f32x4*)(wsb + OBP2 + (size_t)(nt*256 + l*4)*4);
    const char* wp = WS + (size_t)(nt*512 + l*8)*2;
    #pragma unroll 5
    for (int ks = 0; ks < 25; ++ks) {
      bf16x8 a = *(const bf16x8*)(xt + ((lr*1600 + ks*64 + lg*16) ^ ((lr&7)<<4)));
      bf16x8 b = *(const bf16x8*)(wp + (size_t)ks*42*512*2);
      acc = MFMA(a,b,acc);
    }
    *(f32x4*)(wsb + OP2 + ((size_t)(rt*42+nt)*64 + l)*16) = acc;
  }
}

// ------- main persistent kernel: 512 blocks x 1024 threads (16 waves), 16 rows -------
__global__ __launch_bounds__(1024,8) void draw_main(
    const float* __restrict__ noise, const char* __restrict__ wsb, float* __restrict__ out)
{
  extern __shared__ char sm[];
  char* Aenc = sm;               // [16][1792 B] bf16: sigc(784) | hdec(100) | pad
  char* Ahml = sm + 28672;       // [16][512 B]  bf16: hmu(100) pad | hlv(100) pad
  char* Adec = sm + 36864;       // [16][512 B]  bf16: z(100) pad | hdec(100) pad
  float* muv = (float*)(sm + 45056);   // [1600] mu | [1600] lv (f32)

  const int tid = threadIdx.x, l = tid&63, w = tid>>6;   // w in [0,16)
  const int lr = l&15, lg = l>>4;
  const int blk = blockIdx.x;

  float* out_c  = out;
  float* out_mu = out + (size_t)8192*784;
  float* out_lv = out_mu + (size_t)32*8192*100;

  for (int i = tid; i < 16*896; i += 1024) {
    int row = i/896, col = i - row*896;
    unsigned short v = (col<784)? (unsigned short)0x3F00 : (unsigned short)0;
    *(unsigned short*)(Aenc + ((row*1792 + col*2) ^ ((row&7)<<4))) = v;
  }
  for (int i = tid; i < 16*256; i += 1024) {
    int row = i>>8, col = i&255;
    int a = (row*512 + col*2) ^ ((row&7)<<4);
    *(unsigned short*)(Ahml + a) = 0;
    *(unsigned short*)(Adec + a) = 0;
  }

  // wave roles: 0-6 = mu path, 8-14 = lv+dec path, 7/15 = helper (z/store/write only)
  const bool isMu = (w < 7);
  const bool isLv = (w >= 8 && w < 15);
  const bool act  = isMu || isLv;
  const int p = isMu ? w : (w - 8);
  const int axor = (lr&7)<<4;

  const f32x4 z4 = {0.f,0.f,0.f,0.f};
  f32x4 p2j[3] = {z4,z4,z4};
  if (act) {
    size_t pb = OP2 + (((size_t)blk*42 + (isLv?21:0) + p)*64 + l)*16;
    p2j[0] = *(const f32x4*)(wsb + pb);
    p2j[1] = *(const f32x4*)(wsb + pb + (size_t)7*64*16);
    p2j[2] = *(const f32x4*)(wsb + pb + (size_t)14*64*16);
  }
  f32x4 creg[4] = {z4,z4,z4,z4};
  f32x4 hreg = z4;   // hm (mu waves) / hl (lv waves)
  f32x4 hd = z4;     // decoder state (lv waves)
  __syncthreads();

  for (int t = 0; t < 32; ++t) {
    // ---- noise prefetch: 1600 contiguous floats, fully coalesced ----
    float noz[2] = {0.f, 0.f};
    #pragma unroll
    for (int k2=0;k2<2;++k2) {
      int i = tid + k2*1024;
      if (i < 1600)
        noz[k2] = __builtin_nontemporal_load(noise + (size_t)t*819200 + (size_t)blk*1600 + i);
    }

    // ===== encoder GEMM (mu waves: OWEAM, lv waves: OWEAL) =====
    f32x4 ar=z4, az=z4, an=z4, ahn=z4;
    if (act) {
      ar = p2j[0]; az = p2j[1]; an = p2j[2];
      ahn = *(const f32x4*)(wsb + OBGHN + (size_t)(((isLv?7:0)+p)*256 + l*4)*4);
      const char* wr = wsb + (isLv? OWEAL : OWEAM) + (size_t)(p*512 + l*8)*2;
      const char* wz = wr + (size_t)7*512*2;
      const char* wn = wr + (size_t)14*512*2;
      int abase = lr*1792 + lg*16;
      #pragma unroll 4
      for (int ks=0; ks<28; ++ks) {
        bf16x8 a = *(const bf16x8*)(Aenc + ((abase + ks*64) ^ axor));
        size_t so = (size_t)ks*21*512*2;
        ar = MFMA(a, *(const bf16x8*)(wr+so), ar);
        az = MFMA(a, *(const bf16x8*)(wz+so), az);
        an = MFMA(a, *(const bf16x8*)(wn+so), an);
      }
      const char* vr = wsb + (isLv? OWEBL : OWEBM) + (size_t)(p*512 + l*8)*2;
      const char* vz = vr + (size_t)7*512*2;
      const char* vn = vr + (size_t)14*512*2;
      int hb = lr*512 + (isLv?256:0) + lg*16;
      #pragma unroll
      for (int ks=0; ks<4; ++ks) {
        bf16x8 a = *(const bf16x8*)(Ahml + ((hb + ks*64) ^ axor));
        size_t so = (size_t)ks*21*512*2;
        ar  = MFMA(a, *(const bf16x8*)(vr+so), ar);
        az  = MFMA(a, *(const bf16x8*)(vz+so), az);
        ahn = MFMA(a, *(const bf16x8*)(vn+so), ahn);
      }
    }
    __syncthreads();                       // B1: Ahml reads done
    if (act) {
      int col = p*16 + lr;
      #pragma unroll
      for (int e=0;e<4;++e) {
        float rg = sigf(ar[e]);
        float zg = sigf(az[e]);
        float nn = tanhfast(fmaf(rg, ahn[e], an[e]));
        float hnew = nn + zg*(hreg[e] - nn);
        hreg[e] = hnew;
        if (col < 100) {
          int row = lg*4 + e;
          *(unsigned short*)(Ahml + ((row*512 + ((isLv?128:0)+col)*2) ^ ((row&7)<<4))) = f2bf(hnew);
        }
      }
    }
    __syncthreads();                       // B2: hmu/hlv ready

    // ===== heads (mu waves -> mu, lv waves -> lv) =====
    if (isMu) {
      f32x4 am = *(const f32x4*)(wsb + OBH + (size_t)(p*256 + l*4)*4);
      const char* WH = wsb + OWH;
      int hb = lr*512 + lg*16;
      #pragma unroll
      for (int ks=0; ks<4; ++ks) {
        bf16x8 a0 = *(const bf16x8*)(Ahml + ((hb + ks*64) ^ axor));
        am = MFMA(a0, *(const bf16x8*)(WH + ((size_t)(ks*14+p)*512 + l*8)*2), am);
      }
      int col = p*16 + lr;
      if (col < 100) {
        #pragma unroll
        for (int e=0;e<4;++e)
          muv[(lg*4+e)*100 + col] = fmaxf(am[e], 0.f);
      }
    } else if (isLv) {
      f32x4 al = *(const f32x4*)(wsb + OBH + (size_t)((7+p)*256 + l*4)*4);
      const char* WH = wsb + OWH;
      int hb = lr*512 + 256 + lg*16;
      #pragma unroll
      for (int ks=0; ks<4; ++ks) {
        bf16x8 a1 = *(const bf16x8*)(Ahml + ((hb + ks*64) ^ axor));
        al = MFMA(a1, *(const bf16x8*)(WH + ((size_t)((ks+4)*14+7+p)*512 + l*8)*2), al);
      }
      int col = p*16 + lr;
      if (col < 100) {
        #pragma unroll
        for (int e=0;e<4;++e)
          muv[1600 + (lg*4+e)*100 + col] = fmaxf(al[e], 0.f);
      }
    }
    __syncthreads();                       // B3: muv complete

    // ===== z-compute (elementwise) + dense store of mu/lv (plain, L2-merged) =====
    #pragma unroll
    for (int k2=0;k2<2;++k2) {
      int i = tid + k2*1024;
      if (i < 1600) {
        float m  = muv[i];
        float lv = muv[1600 + i];
        float zz = fmaf(noz[k2], __expf(0.5f*lv), m);
        int row = i/100, col = i - row*100;
        *(unsigned short*)(Adec + ((row*512 + col*2) ^ ((row&7)<<4))) = f2bf(zz);
      }
    }
    {
      size_t mb = (size_t)t*819200 + (size_t)blk*1600;
      if (tid < 800) {
        bool m0 = tid < 400;
        int k = m0 ? tid : tid - 400;
        f32x4 v = ((const f32x4*)muv)[m0 ? tid : (tid)];
        v = ((const f32x4*)muv)[(m0 ? 0 : 400) + k];
        *((f32x4*)((m0 ? out_mu : out_lv) + mb) + k) = v;
      }
    }
    __syncthreads();                       // B4: Adec z ready

    // ===== decoder GRU (lv waves) =====
    f32x4 dr=z4, dz=z4, dn=z4, dhn=z4;
    if (isLv) {
      dr  = *(const f32x4*)(wsb + OBDI  + (size_t)(p*256 + l*4)*4);
      dz  = *(const f32x4*)(wsb + OBDI  + (size_t)((p+7)*256 + l*4)*4);
      dn  = *(const f32x4*)(wsb + OBDI  + (size_t)((p+14)*256 + l*4)*4);
      dhn = *(const f32x4*)(wsb + OBDHN + (size_t)(p*256 + l*4)*4);
      const char* br = wsb + OWD + (size_t)(p*512 + l*8)*2;
      const char* bz = br + (size_t)7*512*2;
      const char* bn = br + (size_t)14*512*2;
      int abase = lr*512 + lg*16;
      #pragma unroll
      for (int ks=0; ks<8; ++ks) {
        bf16x8 a = *(const bf16x8*)(Adec + ((abase + ks*64) ^ axor));
        size_t so = (size_t)ks*21*512*2;
        dr = MFMA(a, *(const bf16x8*)(br+so), dr);
        dz = MFMA(a, *(const bf16x8*)(bz+so), dz);
        if (ks<4) dn  = MFMA(a, *(const bf16x8*)(bn+so), dn);
        else      dhn = MFMA(a, *(const bf16x8*)(bn+so), dhn);
      }
    }
    __syncthreads();                       // B5: Adec reads done
    if (isLv) {
      int col = p*16 + lr;
      #pragma unroll
      for (int e=0;e<4;++e) {
        float rg = sigf(dr[e]);
        float zg = sigf(dz[e]);
        float nn = tanhfast(fmaf(rg, dhn[e], dn[e]));
        float hnew = nn + zg*(hd[e] - nn);
        hd[e] = hnew;
        if (col < 100) {
          int row = lg*4 + e;
          unsigned short hb2 = f2bf(hnew);
          *(unsigned short*)(Adec + ((row*512 + (128+col)*2) ^ ((row&7)<<4))) = hb2;
          *(unsigned short*)(Aenc + ((row*1792 + (784+col)*2) ^ ((row&7)<<4))) = hb2;
        }
      }
    }
    __syncthreads();                       // B6: new hdec visible

    // ===== canvas write GEMM: all 16 waves, nt = w + 16*rep =====
    {
      const char* WW = wsb + OWW;
      #pragma unroll
      for (int rep=0; rep<4; ++rep) {
        int nt = w + rep*16;
        if (nt < 49) {
          f32x4 c = creg[rep];
          int abase = lr*512 + 256 + lg*16;
          #pragma unroll
          for (int ks=0; ks<4; ++ks) {
            bf16x8 a = *(const bf16x8*)(Adec + ((abase + ks*64) ^ axor));
            c = MFMA(a, *(const bf16x8*)(WW + ((size_t)(ks*49+nt)*512 + l*8)*2), c);
          }
          f32x4 bw = *(const f32x4*)(wsb + OBWR + (size_t)(nt*256 + l*4)*4);
          c = c + bw;
          creg[rep] = c;
          #pragma unroll
          for (int e=0;e<4;++e) {
            float s = sigf(c[e]);
            int orow = lg*4 + e;
            int col = nt*16 + lr;
            if (t < 31) {
              *(unsigned short*)(Aenc + ((orow*1792 + col*2) ^ ((orow&7)<<4))) = f2bf(s);
            } else {
              out_c[(size_t)(blk*16+orow)*784 + col] = s;
            }
          }
        }
      }
    }
    __syncthreads();                       // B7: sigc ready for next step
  }
}

extern "C" void kernel_launch(void* const* d_in, const int* in_sizes, int n_in,
                              void* d_out, int out_size, void* d_ws, size_t ws_size,
                              hipStream_t stream) {
  (void)in_sizes; (void)n_in; (void)out_size; (void)ws_size;
  const float* x      = (const float*)d_in[0];
  const float* noise  = (const float*)d_in[1];
  const float* ih_mu  = (const float*)d_in[2];
  const float* whh_mu = (const float*)d_in[3];
  const float* bih_mu = (const float*)d_in[4];
  const float* bhh_mu = (const float*)d_in[5];
  const float* ih_lv  = (const float*)d_in[6];
  const float* whh_lv = (const float*)d_in[7];
  const float* bih_lv = (const float*)d_in[8];
  const float* bhh_lv = (const float*)d_in[9];
  const float* wmu    = (const float*)d_in[10];
  const float* bmu    = (const float*)d_in[11];
  const float* wlv    = (const float*)d_in[12];
  const float* blv    = (const float*)d_in[13];
  const float* wih_dec= (const float*)d_in[14];
  const float* whh_dec= (const float*)d_in[15];
  const float* bih_dec= (const float*)d_in[16];
  const float* bhh_dec= (const float*)d_in[17];
  const float* wwrite = (const float*)d_in[18];
  const float* bwrite = (const float*)d_in[19];
  char* wsb = (char*)d_ws;
  float* out = (float*)d_out;

  (void)hipFuncSetAttribute(reinterpret_cast<const void*>(draw_main),
                            hipFuncAttributeMaxDynamicSharedMemorySize, 57856);

  init_pack<<<5888, 256, 0, stream>>>(ih_mu, whh_mu, bih_mu, bhh_mu,
                                      ih_lv, whh_lv, bih_lv, bhh_lv,
                                      wmu, bmu, wlv, blv,
                                      wih_dec, whh_dec, bih_dec, bhh_dec,
                                      wwrite, bwrite, wsb);
  init_p2<<<512, 512, 0, stream>>>(x, wsb);
  draw_main<<<512, 1024, 57856, stream>>>(noise, wsb, out);
}